// Round 1
// baseline (202.090 us; speedup 1.0000x reference)
//
#include <hip/hip_runtime.h>

// VersorRotorRNN: B=16, S=256, N=16, D=6, H=16, 32 blades (Cl(5,0)).
// Segmented parallel scan over S: normalize() is scale-invariant and the
// geometric product is associative, so psi_t = N(dr_t (x) ... (x) dr_1).
// SEG=16 segments of L=16 steps.

#define EPS 1e-8f

// --- compile-time Cayley sign table: sgn(i,j) for C[i,j,i^j] ---
struct SgnTab { float v[32][32]; };
constexpr SgnTab make_sgn() {
    SgnTab t{};
    for (int i = 0; i < 32; ++i)
        for (int j = 0; j < 32; ++j) {
            int a = i >> 1, s = 0;
            while (a) {
                int x = a & j;
                while (x) { s += x & 1; x >>= 1; }
                a >>= 1;
            }
            t.v[i][j] = (s & 1) ? -1.0f : 1.0f;
        }
    return t;
}
__device__ constexpr SgnTab SG = make_sgn();

// psi <- normalize(a (x) psi); a unmodified. All indices compile-time after
// unroll -> signs fold into v_fma operand negation; arrays become registers.
__device__ __forceinline__ void gp_norm(const float* __restrict__ a,
                                        float* __restrict__ psi) {
    float np[32];
#pragma unroll
    for (int k = 0; k < 32; ++k) np[k] = 0.0f;
#pragma unroll
    for (int i = 0; i < 32; ++i) {
#pragma unroll
        for (int j = 0; j < 32; ++j) {
            np[i ^ j] = fmaf(SG.v[i][j] * a[i], psi[j], np[i ^ j]);
        }
    }
    float s0 = 0.f, s1 = 0.f, s2 = 0.f, s3 = 0.f;
#pragma unroll
    for (int k = 0; k < 32; k += 4) {
        s0 = fmaf(np[k],     np[k],     s0);
        s1 = fmaf(np[k + 1], np[k + 1], s1);
        s2 = fmaf(np[k + 2], np[k + 2], s2);
        s3 = fmaf(np[k + 3], np[k + 3], s3);
    }
    float rs = rsqrtf((s0 + s1) + (s2 + s3) + EPS);
#pragma unroll
    for (int k = 0; k < 32; ++k) psi[k] = np[k] * rs;
}

// ---------------- pass 1: per-segment products -------------------
// thread u: h = u&15, bn = (u>>4)&255, s = u>>12.  Writes Q[chain][s][32].
__global__ __launch_bounds__(256, 1) void k_seg(
        const float* __restrict__ x, const float* __restrict__ W_in,
        const float* __restrict__ b_in, float* __restrict__ Q) {
    __shared__ float WL[3072];  // [(d*32+c)*16 + h] = W_in[d][h*32+c]
    __shared__ float BL[512];   // [c*16 + h]        = b_in[h*32+c]
    const int tid = threadIdx.x;
    for (int idx = tid; idx < 3072; idx += 256) {
        int h = idx & 15, dc = idx >> 4, c = dc & 31, d = dc >> 5;
        WL[idx] = W_in[d * 512 + h * 32 + c];
    }
    for (int idx = tid; idx < 512; idx += 256) {
        int h = idx & 15, c = idx >> 4;
        BL[idx] = b_in[h * 32 + c];
    }
    __syncthreads();

    const unsigned u = blockIdx.x * 256 + tid;
    const int h = u & 15, bn = (u >> 4) & 255, s = u >> 12;
    const int b = bn >> 4, n = bn & 15;
    const float* WLh = WL + h;
    const float* BLh = BL + h;

    float P[32];
#pragma unroll
    for (int k = 0; k < 32; ++k) P[k] = 0.0f;
    P[0] = 1.0f;  // identity rotor

    for (int i = 0; i < 16; ++i) {
        const int t = s * 16 + i;
        const float* xp = x + ((b * 256 + t) * 16 + n) * 6;
        float xv[6];
#pragma unroll
        for (int d = 0; d < 6; ++d) xv[d] = xp[d];
        float uu[32];
#pragma unroll
        for (int c = 0; c < 32; ++c) uu[c] = BLh[c * 16];
#pragma unroll
        for (int d = 0; d < 6; ++d)
#pragma unroll
            for (int c = 0; c < 32; ++c)
                uu[c] = fmaf(xv[d], WLh[(d * 32 + c) * 16], uu[c]);
        uu[0] += 1.0f;           // delta_r (unnormalized; scale cancels)
        gp_norm(uu, P);
    }
    const int chain = bn * 16 + h;
    float4* qp = (float4*)(Q + (chain * 16 + s) * 32);
#pragma unroll
    for (int r = 0; r < 8; ++r)
        qp[r] = make_float4(P[4 * r], P[4 * r + 1], P[4 * r + 2], P[4 * r + 3]);
}

// ---------------- pass 2: exclusive scan over segments (in place) ----------
__global__ __launch_bounds__(64, 1) void k_scan(float* __restrict__ Q) {
    const int c = blockIdx.x * 64 + threadIdx.x;  // chain id, 4096
    float P[32];
#pragma unroll
    for (int k = 0; k < 32; ++k) P[k] = 0.0f;
    P[0] = 1.0f;  // psi0 = identity
    float4* qp = (float4*)(Q + c * 512);
    for (int s = 0; s < 16; ++s) {
        float Qs[32];
#pragma unroll
        for (int r = 0; r < 8; ++r) {
            float4 v = qp[s * 8 + r];
            Qs[4 * r] = v.x; Qs[4 * r + 1] = v.y;
            Qs[4 * r + 2] = v.z; Qs[4 * r + 3] = v.w;
        }
        // write exclusive prefix Pre_s over Q_s slot
#pragma unroll
        for (int r = 0; r < 8; ++r)
            qp[s * 8 + r] = make_float4(P[4 * r], P[4 * r + 1],
                                        P[4 * r + 2], P[4 * r + 3]);
        gp_norm(Qs, P);  // P = N(Q_s (x) P)
    }
}

// ---------------- pass 3: apply interior + project + write output ----------
__global__ __launch_bounds__(256, 1) void k_apply(
        const float* __restrict__ x, const float* __restrict__ W_in,
        const float* __restrict__ b_in, const float* __restrict__ W_out,
        const float* __restrict__ b_out, const float* __restrict__ Pre,
        float* __restrict__ out) {
    __shared__ float WL[3072];  // as in k_seg
    __shared__ float BL[512];
    __shared__ float WO[3072];  // [(k*6+d)*16 + h] = W_out[(h*32+k)*6+d]
    const int tid = threadIdx.x;
    for (int idx = tid; idx < 3072; idx += 256) {
        int h = idx & 15, dc = idx >> 4;
        int c = dc & 31, d = dc >> 5;
        WL[idx] = W_in[d * 512 + h * 32 + c];
        int dd = dc % 6, k = dc / 6;
        WO[idx] = W_out[(h * 32 + k) * 6 + dd];
    }
    for (int idx = tid; idx < 512; idx += 256) {
        int h = idx & 15, c = idx >> 4;
        BL[idx] = b_in[h * 32 + c];
    }
    __syncthreads();

    const unsigned u = blockIdx.x * 256 + tid;
    const int h = u & 15, bn = (u >> 4) & 255, s = u >> 12;
    const int b = bn >> 4, n = bn & 15;
    const int chain = bn * 16 + h;
    const float* WLh = WL + h;
    const float* BLh = BL + h;
    const float* WOh = WO + h;

    float R[32];
    {
        const float4* pp = (const float4*)(Pre + (chain * 16 + s) * 32);
#pragma unroll
        for (int r = 0; r < 8; ++r) {
            float4 v = pp[r];
            R[4 * r] = v.x; R[4 * r + 1] = v.y;
            R[4 * r + 2] = v.z; R[4 * r + 3] = v.w;
        }
    }
    float bo[6];
#pragma unroll
    for (int d = 0; d < 6; ++d) bo[d] = b_out[d];

    for (int i = 0; i < 16; ++i) {
        const int t = s * 16 + i;
        const float* xp = x + ((b * 256 + t) * 16 + n) * 6;
        float xv[6];
#pragma unroll
        for (int d = 0; d < 6; ++d) xv[d] = xp[d];
        float uu[32];
#pragma unroll
        for (int c = 0; c < 32; ++c) uu[c] = BLh[c * 16];
#pragma unroll
        for (int d = 0; d < 6; ++d)
#pragma unroll
            for (int c = 0; c < 32; ++c)
                uu[c] = fmaf(xv[d], WLh[(d * 32 + c) * 16], uu[c]);
        uu[0] += 1.0f;
        gp_norm(uu, R);  // R = psi_t

        float pd[6] = {0.f, 0.f, 0.f, 0.f, 0.f, 0.f};
#pragma unroll
        for (int k = 0; k < 32; ++k)
#pragma unroll
            for (int d = 0; d < 6; ++d)
                pd[d] = fmaf(R[k], WOh[(k * 6 + d) * 16], pd[d]);
        // sum over the 16 h-lanes of this (b,n)
#pragma unroll
        for (int m = 1; m < 16; m <<= 1)
#pragma unroll
            for (int d = 0; d < 6; ++d)
                pd[d] += __shfl_xor(pd[d], m, 16);
        if ((tid & 15) == 0) {
            float* op = out + ((b * 256 + t) * 16 + n) * 6;
#pragma unroll
            for (int d = 0; d < 6; ++d) op[d] = xv[d] + bo[d] + pd[d];
        }
    }
}

extern "C" void kernel_launch(void* const* d_in, const int* in_sizes, int n_in,
                              void* d_out, int out_size, void* d_ws, size_t ws_size,
                              hipStream_t stream) {
    (void)in_sizes; (void)n_in; (void)out_size; (void)ws_size;
    const float* x     = (const float*)d_in[0];  // [16,256,16,6]
    const float* W_in  = (const float*)d_in[1];  // [6,512]
    const float* b_in  = (const float*)d_in[2];  // [512]
    const float* W_out = (const float*)d_in[3];  // [512,6]
    const float* b_out = (const float*)d_in[4];  // [6]
    float* out = (float*)d_out;                  // [16,256,16,6]
    float* Q   = (float*)d_ws;                   // 4096*16*32 floats = 8 MB

    k_seg  <<<256, 256, 0, stream>>>(x, W_in, b_in, Q);
    k_scan <<< 64,  64, 0, stream>>>(Q);
    k_apply<<<256, 256, 0, stream>>>(x, W_in, b_in, W_out, b_out, Q, out);
}